// Round 3
// baseline (492.200 us; speedup 1.0000x reference)
//
#include <hip/hip_runtime.h>

using bf16x8 = __attribute__((ext_vector_type(8))) __bf16;
using f32x4  = __attribute__((ext_vector_type(4))) float;

#define AS1 __attribute__((address_space(1)))
#define AS3 __attribute__((address_space(3)))

__device__ __forceinline__ unsigned short f2bf(float f) {
    unsigned int x = __float_as_uint(f);
    x += 0x7fffu + ((x >> 16) & 1u);   // RNE
    return (unsigned short)(x >> 16);
}

// ---------------- convert x fp32 -> bf16 ----------------
__global__ void cvt_f32_bf16_kernel(const float4* __restrict__ in, ushort4* __restrict__ out, int n4) {
    int stride = gridDim.x * blockDim.x;
    for (int i = blockIdx.x * blockDim.x + threadIdx.x; i < n4; i += stride) {
        float4 v = in[i];
        ushort4 o;
        o.x = f2bf(v.x); o.y = f2bf(v.y); o.z = f2bf(v.z); o.w = f2bf(v.w);
        out[i] = o;
    }
}

// ---------------- transpose W (K x N) fp32 -> Wt (N x K) bf16 ----------------
__global__ void transpose_f32_bf16_kernel(const float* __restrict__ W, unsigned short* __restrict__ Wt,
                                          int K, int N) {
    __shared__ float tile[32][33];
    int n0 = blockIdx.x << 5, k0 = blockIdx.y << 5;
    int tx = threadIdx.x, ty = threadIdx.y;
#pragma unroll
    for (int i = 0; i < 32; i += 8)
        tile[ty + i][tx] = W[(size_t)(k0 + ty + i) * N + (n0 + tx)];
    __syncthreads();
#pragma unroll
    for (int i = 0; i < 32; i += 8)
        Wt[(size_t)(n0 + ty + i) * K + (k0 + tx)] = f2bf(tile[tx][ty + i]);
}

// ================= 256x256 8-wave pipelined GEMM: C = A[M,K] * Bt[N,K]^T =================
// BK=32, 3 LDS buffers (96KB), counted vmcnt(8) (2 tiles in flight), raw s_barrier,
// setprio around MFMA clusters, bijective XCD swizzle, (row&3)<<4 XOR LDS swizzle.
__device__ __forceinline__ void stage32(const unsigned short* Ag, const unsigned short* Bg,
                                        int kb, int K, char* buf, int tid) {
#pragma unroll
    for (int r = 0; r < 2; ++r) {
        int i = (r << 9) + tid;             // 0..1023 16B-chunks of A-tile (256 rows x 64B)
        int row = i >> 2, slot = i & 3;
        int srcb = row * (K << 1) + (kb << 1) + ((slot ^ (row & 3)) << 4);
        __builtin_amdgcn_global_load_lds((AS1 unsigned int*)((const char*)Ag + srcb),
                                         (AS3 unsigned int*)(buf + (i << 4)), 16, 0, 0);
    }
#pragma unroll
    for (int r = 0; r < 2; ++r) {
        int i = (r << 9) + tid;
        int row = i >> 2, slot = i & 3;
        int srcb = row * (K << 1) + (kb << 1) + ((slot ^ (row & 3)) << 4);
        __builtin_amdgcn_global_load_lds((AS1 unsigned int*)((const char*)Bg + srcb),
                                         (AS3 unsigned int*)(buf + 16384 + (i << 4)), 16, 0, 0);
    }
}

__device__ __forceinline__ bf16x8 rdfrag(const char* base, int row, int lane) {
    int off = (row << 6) + (((lane >> 4) << 4) ^ ((row & 3) << 4));
    return *(const bf16x8*)(base + off);
}

template <int OUTMODE>  // 0: bf16 out, 1: fp32 out + bias
__global__ __launch_bounds__(512, 2)
void gemm256_kernel(const unsigned short* __restrict__ A, const unsigned short* __restrict__ Bt,
                    unsigned short* __restrict__ obf, float* __restrict__ of32,
                    const float* __restrict__ bias, int M, int N, int K, int ntx) {
    __shared__ char smem[3 * 32768];
    int tid = threadIdx.x, lane = tid & 63, w = tid >> 6;
    int wm = w >> 2, wn = w & 3;

    // bijective XCD-aware remap (m204 variant)
    int nwg = gridDim.x;
    int q = nwg >> 3, r = nwg & 7;
    int orig = blockIdx.x;
    int xcd = orig & 7, lin = orig >> 3;
    int wg = (xcd < r ? xcd * (q + 1) : r * (q + 1) + (xcd - r) * q) + lin;
    int by = wg / ntx, bx = wg - by * ntx;
    int m0 = by << 8, n0 = bx << 8;
    const unsigned short* Ag = A + (size_t)m0 * K;
    const unsigned short* Bg = Bt + (size_t)n0 * K;
    int nkt = K >> 5;

    f32x4 zz = {0.f, 0.f, 0.f, 0.f};
    f32x4 acc[8][4];
#pragma unroll
    for (int a = 0; a < 8; ++a)
#pragma unroll
        for (int b = 0; b < 4; ++b) acc[a][b] = zz;

    stage32(Ag, Bg, 0, K, smem, tid);
    stage32(Ag, Bg, 32, K, smem + 32768, tid);

    for (int t = 0; t < nkt; ++t) {
        int p = t % 3;
        char* Ab = smem + p * 32768;
        char* Bb = Ab + 16384;
        if (t + 2 < nkt) stage32(Ag, Bg, (t + 2) << 5, K, smem + ((t + 2) % 3) * 32768, tid);
        if (t + 3 <= nkt)      asm volatile("s_waitcnt vmcnt(8)" ::: "memory");
        else if (t + 2 == nkt) asm volatile("s_waitcnt vmcnt(4)" ::: "memory");
        else                   asm volatile("s_waitcnt vmcnt(0)" ::: "memory");
        asm volatile("s_barrier" ::: "memory");

        bf16x8 bfr[4], af[8];
#pragma unroll
        for (int f = 0; f < 4; ++f) bfr[f] = rdfrag(Bb, (wn << 6) + (f << 4) + (lane & 15), lane);
#pragma unroll
        for (int f = 0; f < 8; ++f) af[f] = rdfrag(Ab, (wm << 7) + (f << 4) + (lane & 15), lane);

        __builtin_amdgcn_s_setprio(1);
#pragma unroll
        for (int fm = 0; fm < 4; ++fm)
#pragma unroll
            for (int fn = 0; fn < 4; ++fn)
                acc[fm][fn] = __builtin_amdgcn_mfma_f32_16x16x32_bf16(af[fm], bfr[fn], acc[fm][fn], 0, 0, 0);
        __builtin_amdgcn_s_setprio(0);
        asm volatile("s_barrier" ::: "memory");
        __builtin_amdgcn_s_setprio(1);
#pragma unroll
        for (int fm = 4; fm < 8; ++fm)
#pragma unroll
            for (int fn = 0; fn < 4; ++fn)
                acc[fm][fn] = __builtin_amdgcn_mfma_f32_16x16x32_bf16(af[fm], bfr[fn], acc[fm][fn], 0, 0, 0);
        __builtin_amdgcn_s_setprio(0);
        asm volatile("s_barrier" ::: "memory");
    }

    int rbase = m0 + (wm << 7) + ((lane >> 4) << 2);
    int cbase = n0 + (wn << 6) + (lane & 15);
    if (OUTMODE == 0) {
#pragma unroll
        for (int fm = 0; fm < 8; ++fm)
#pragma unroll
            for (int j = 0; j < 4; ++j) {
                size_t ro = (size_t)(rbase + (fm << 4) + j) * N;
#pragma unroll
                for (int fn = 0; fn < 4; ++fn)
                    obf[ro + cbase + (fn << 4)] = f2bf(acc[fm][fn][j]);
            }
    } else {
        float bv[4];
#pragma unroll
        for (int fn = 0; fn < 4; ++fn) bv[fn] = bias[cbase + (fn << 4)];
#pragma unroll
        for (int fm = 0; fm < 8; ++fm)
#pragma unroll
            for (int j = 0; j < 4; ++j) {
                size_t ro = (size_t)(rbase + (fm << 4) + j) * N;
#pragma unroll
                for (int fn = 0; fn < 4; ++fn)
                    of32[ro + cbase + (fn << 4)] = acc[fm][fn][j] + bv[fn];
            }
    }
}

// ---------------- covariance via MFMA: S[bh][c][e] = sum_n k[n,c]*q[n,e], + channel norms ----
__global__ __launch_bounds__(256)
void cov_mfma_kernel(const unsigned short* __restrict__ qkv, float* __restrict__ S,
                     float* __restrict__ qn2, float* __restrict__ kn2) {
    __shared__ unsigned short Kl[96 * 40];   // [channel][token], stride 40 ushorts (80B)
    __shared__ unsigned short Ql[96 * 40];
    int bh = blockIdx.x;
    int b = bh >> 3, h = bh & 7;
    int tok0 = blockIdx.y * 448;
    int tid = threadIdx.x;
    int lane = tid & 63, w = tid >> 6;
    int wr = w & 1, wc = w >> 1;
    int rot = tid & 7;

    f32x4 zz = {0.f, 0.f, 0.f, 0.f};
    f32x4 acc[3][3];
#pragma unroll
    for (int a = 0; a < 3; ++a)
#pragma unroll
        for (int c = 0; c < 3; ++c) acc[a][c] = zz;
    float qn = 0.f, kn = 0.f;

    const uint4* qg = (const uint4*)qkv;   // qkv row = 288 uint4

    for (int step = 0; step < 14; ++step) {
        int tokBase = b * 3136 + tok0 + (step << 5);
        __syncthreads();
#pragma unroll
        for (int r = 0; r < 3; ++r) {
            int idx = (r << 8) + tid;          // 0..767 ; 0..383 = Q, 384..767 = K
            int isK = idx >= 384;
            int j = isK ? idx - 384 : idx;
            int tok = j / 12, c = j % 12;
            uint4 u = qg[(size_t)(tokBase + tok) * 288 + h * 12 + (isK ? 96 : 0) + c];
            unsigned short* dst = isK ? Kl : Ql;
            const unsigned short* us = (const unsigned short*)&u;
#pragma unroll
            for (int i = 0; i < 8; ++i) {
                int e = (i + rot) & 7;
                dst[(c * 8 + e) * 40 + tok] = us[e];
            }
        }
        __syncthreads();
        if (tid < 96) {
#pragma unroll
            for (int t = 0; t < 4; ++t) {
                bf16x8 v = *(const bf16x8*)((const char*)Ql + tid * 80 + (t << 4));
#pragma unroll
                for (int i = 0; i < 8; ++i) { float f = (float)v[i]; qn = fmaf(f, f, qn); }
            }
        } else if (tid >= 128 && tid < 224) {
            int c = tid - 128;
#pragma unroll
            for (int t = 0; t < 4; ++t) {
                bf16x8 v = *(const bf16x8*)((const char*)Kl + c * 80 + (t << 4));
#pragma unroll
                for (int i = 0; i < 8; ++i) { float f = (float)v[i]; kn = fmaf(f, f, kn); }
            }
        }
        int kbyte = (lane >> 4) << 4;
        bf16x8 af[3], bfv[3];
#pragma unroll
        for (int f = 0; f < 3; ++f)
            af[f] = *(const bf16x8*)((const char*)Kl + (wr * 48 + f * 16 + (lane & 15)) * 80 + kbyte);
#pragma unroll
        for (int f = 0; f < 3; ++f)
            bfv[f] = *(const bf16x8*)((const char*)Ql + (wc * 48 + f * 16 + (lane & 15)) * 80 + kbyte);
#pragma unroll
        for (int fm = 0; fm < 3; ++fm)
#pragma unroll
            for (int fn = 0; fn < 3; ++fn)
                acc[fm][fn] = __builtin_amdgcn_mfma_f32_16x16x32_bf16(af[fm], bfv[fn], acc[fm][fn], 0, 0, 0);
    }

    float* Sb = S + (size_t)bh * 9216;
    int rloc = wr * 48 + ((lane >> 4) << 2);
    int cloc = wc * 48 + (lane & 15);
#pragma unroll
    for (int fm = 0; fm < 3; ++fm)
#pragma unroll
        for (int fn = 0; fn < 3; ++fn)
#pragma unroll
            for (int j = 0; j < 4; ++j)
                atomicAdd(&Sb[(rloc + fm * 16 + j) * 96 + cloc + fn * 16], acc[fm][fn][j]);
    if (tid < 96) atomicAdd(&qn2[bh * 96 + tid], qn);
    if (tid >= 128 && tid < 224) atomicAdd(&kn2[bh * 96 + tid - 128], kn);
}

// ---------------- softmax over e of S[c,e]/(||k_c||*||q_e||)*temp[h] -> bf16 attn ----------------
__global__ __launch_bounds__(128)
void softmax_kernel(const float* __restrict__ S, const float* __restrict__ qn2,
                    const float* __restrict__ kn2, const float* __restrict__ temp,
                    unsigned short* __restrict__ attnb) {
    int bh = blockIdx.x, h = bh & 7;
    __shared__ float Sl[96 * 97];
    __shared__ float qinv[96];
    int tid = threadIdx.x;
    const float* Sg = S + (size_t)bh * 9216;
    for (int i = tid; i < 9216; i += 128) Sl[(i / 96) * 97 + (i % 96)] = Sg[i];
    if (tid < 96) qinv[tid] = 1.f / fmaxf(sqrtf(qn2[bh * 96 + tid]), 1e-12f);
    __syncthreads();
    if (tid < 96) {
        int c = tid;
        float scale = (1.f / fmaxf(sqrtf(kn2[bh * 96 + c]), 1e-12f)) * temp[h];
        float* row = &Sl[c * 97];
        float mx = -3.4e38f;
        for (int e = 0; e < 96; ++e) {
            float v = row[e] * scale * qinv[e];
            row[e] = v;
            mx = fmaxf(mx, v);
        }
        float s = 0.f;
        for (int e = 0; e < 96; ++e) {
            float p = __expf(row[e] - mx);
            row[e] = p;
            s += p;
        }
        float inv = 1.f / s;
        unsigned short* ab = attnb + (size_t)bh * 9216 + c * 96;
        for (int e = 0; e < 96; ++e) ab[e] = f2bf(row[e] * inv);
    }
}

// ---------------- Y[n, h*96+c] = sum_e attn[bh][c][e] * v[n][e]  (MFMA, token-major) ----------------
__global__ __launch_bounds__(256)
void attn_v_kernel(const unsigned short* __restrict__ qkv, const unsigned short* __restrict__ attnb,
                   unsigned short* __restrict__ Y) {
    int n0 = blockIdx.x << 6;
    int bh = blockIdx.y;
    int b = bh >> 3, h = bh & 7;
    __shared__ unsigned short Asm[96 * 104];
    __shared__ unsigned short Vs[64 * 104];
    int tid = threadIdx.x;
    int lane = tid & 63, w = tid >> 6;

    const unsigned int* ag = (const unsigned int*)(attnb + (size_t)bh * 9216);
#pragma unroll
    for (int r = 0; r < 18; ++r) {
        int i2 = (r << 8) + tid;
        int c = i2 / 48, ep = i2 % 48;
        *(unsigned int*)&Asm[c * 104 + (ep << 1)] = ag[i2];
    }
    size_t vbase = (size_t)(b * 3136 + n0) * 1152 + 768 + h * 48;
    const unsigned int* vg = (const unsigned int*)qkv;
#pragma unroll
    for (int r = 0; r < 12; ++r) {
        int i2 = (r << 8) + tid;
        int row = i2 / 48, ep = i2 % 48;
        *(unsigned int*)&Vs[row * 104 + (ep << 1)] = vg[vbase + (size_t)row * 1152 + ep];
    }
    __syncthreads();

    f32x4 zz = {0.f, 0.f, 0.f, 0.f};
    f32x4 acc[6];
#pragma unroll
    for (int f = 0; f < 6; ++f) acc[f] = zz;

#pragma unroll
    for (int ks = 0; ks < 3; ++ks) {
        int kbyte = (ks << 6) + ((lane >> 4) << 4);
        bf16x8 av = *(const bf16x8*)((const char*)Vs + ((w << 4) + (lane & 15)) * 208 + kbyte);
#pragma unroll
        for (int fn = 0; fn < 6; ++fn) {
            bf16x8 bv = *(const bf16x8*)((const char*)Asm + ((fn << 4) + (lane & 15)) * 208 + kbyte);
            acc[fn] = __builtin_amdgcn_mfma_f32_16x16x32_bf16(av, bv, acc[fn], 0, 0, 0);
        }
    }

    int rlocal = n0 + (w << 4) + ((lane >> 4) << 2);
#pragma unroll
    for (int fn = 0; fn < 6; ++fn)
#pragma unroll
        for (int j = 0; j < 4; ++j)
            Y[(size_t)(b * 3136 + rlocal + j) * 768 + h * 96 + (fn << 4) + (lane & 15)] = f2bf(acc[fn][j]);
}

// ---------------- launch ----------------
extern "C" void kernel_launch(void* const* d_in, const int* in_sizes, int n_in,
                              void* d_out, int out_size, void* d_ws, size_t ws_size,
                              hipStream_t stream) {
    const float* x     = (const float*)d_in[0];
    const float* Wqkv  = (const float*)d_in[1];
    const float* temp  = (const float*)d_in[2];
    const float* Wproj = (const float*)d_in[3];
    const float* bproj = (const float*)d_in[4];
    float* out = (float*)d_out;
    char* ws = (char*)d_ws;

    unsigned short* xbf    = (unsigned short*)(ws);                 //  77,070,336
    unsigned short* qkvbf  = (unsigned short*)(ws + 77070336);      // 231,211,008
    unsigned short* wqkvt  = (unsigned short*)(ws + 308281344);     //   3,538,944
    unsigned short* wprojt = (unsigned short*)(ws + 311820288);     //   1,179,648
    float*          Sbuf   = (float*)        (ws + 312999936);      //   4,718,592
    float*          qn2    = (float*)        (ws + 317718528);      //      49,152
    float*          kn2    = (float*)        (ws + 317767680);      //      49,152
    unsigned short* attnb  = (unsigned short*)(ws + 317816832);     //   2,359,296
    unsigned short* ybf    = xbf;  // alias: x_bf16 dead after GEMM1

    hipMemsetAsync(Sbuf, 0, 4718592 + 49152 + 49152, stream);

    cvt_f32_bf16_kernel<<<2048, 256, 0, stream>>>((const float4*)x, (ushort4*)xbf, 38535168 / 4);
    transpose_f32_bf16_kernel<<<dim3(72, 24), dim3(32, 8), 0, stream>>>(Wqkv, wqkvt, 768, 2304);
    transpose_f32_bf16_kernel<<<dim3(24, 24), dim3(32, 8), 0, stream>>>(Wproj, wprojt, 768, 768);

    // qkv = x @ Wqkv   [50176 x 2304], bf16 out
    gemm256_kernel<0><<<196 * 9, 512, 0, stream>>>(xbf, wqkvt, qkvbf, nullptr, nullptr,
                                                   50176, 2304, 768, 9);
    // S = K^T Q (per bh), + channel norms
    cov_mfma_kernel<<<dim3(128, 7), 256, 0, stream>>>(qkvbf, Sbuf, qn2, kn2);
    // attn = softmax(S / (|k||q|) * temp)
    softmax_kernel<<<128, 128, 0, stream>>>(Sbuf, qn2, kn2, temp, attnb);
    // Y = V * attn^T  (token-major)
    attn_v_kernel<<<dim3(49, 128), 256, 0, stream>>>(qkvbf, attnb, ybf);
    // out = Y @ Wproj + b   fp32
    gemm256_kernel<1><<<196 * 3, 512, 0, stream>>>(ybf, wprojt, nullptr, out, bproj,
                                                   50176, 768, 768, 3);
}

// Round 4
// 477.078 us; speedup vs baseline: 1.0317x; 1.0317x over previous
//
#include <hip/hip_runtime.h>

using bf16x8 = __attribute__((ext_vector_type(8))) __bf16;
using f32x4  = __attribute__((ext_vector_type(4))) float;

#define AS1 __attribute__((address_space(1)))
#define AS3 __attribute__((address_space(3)))

__device__ __forceinline__ unsigned short f2bf(float f) {
    unsigned int x = __float_as_uint(f);
    x += 0x7fffu + ((x >> 16) & 1u);   // RNE
    return (unsigned short)(x >> 16);
}

// ---------------- convert x fp32 -> bf16 ----------------
__global__ void cvt_f32_bf16_kernel(const float4* __restrict__ in, ushort4* __restrict__ out, int n4) {
    int stride = gridDim.x * blockDim.x;
    for (int i = blockIdx.x * blockDim.x + threadIdx.x; i < n4; i += stride) {
        float4 v = in[i];
        ushort4 o;
        o.x = f2bf(v.x); o.y = f2bf(v.y); o.z = f2bf(v.z); o.w = f2bf(v.w);
        out[i] = o;
    }
}

// ---------------- transpose W (K x N) fp32 -> Wt (N x K) bf16 ----------------
__global__ void transpose_f32_bf16_kernel(const float* __restrict__ W, unsigned short* __restrict__ Wt,
                                          int K, int N) {
    __shared__ float tile[32][33];
    int n0 = blockIdx.x << 5, k0 = blockIdx.y << 5;
    int tx = threadIdx.x, ty = threadIdx.y;
#pragma unroll
    for (int i = 0; i < 32; i += 8)
        tile[ty + i][tx] = W[(size_t)(k0 + ty + i) * N + (n0 + tx)];
    __syncthreads();
#pragma unroll
    for (int i = 0; i < 32; i += 8)
        Wt[(size_t)(n0 + ty + i) * K + (k0 + tx)] = f2bf(tile[tx][ty + i]);
}

// ================= 256x128 8-wave pipelined GEMM: C = A[M,K] * Bt[N,K]^T =================
// BK=64. LDS: A triple-buffered (3x32KB) + B double-buffered (2x16KB) = 128KB.
// Counted vmcnt(4): A(t+2) stays in flight across the end-of-tile barrier (~2-tile HBM cover),
// B(t+1) gets ~1-tile cover (L2-hot). (row&7)<<4 XOR swizzle (proven 0-conflict at 128B rows).
// 2 phases/K-tile: 16 MFMA each, barrier/setprio rhythm (T3+T5). Bijective XCD remap (T1).

__device__ __forceinline__ void stageA64(const unsigned short* Ag, int kb, int K, char* dst, int tid) {
    // 256x64 bf16 = 2048 16B-chunks; thread handles chunks tid + {0,512,1024,1536}
#pragma unroll
    for (int r = 0; r < 4; ++r) {
        int i = (r << 9) + tid;
        int row = i >> 3, s = i & 7;
        size_t srcb = (size_t)row * ((size_t)K << 1) + ((size_t)kb << 1) + ((s ^ (row & 7)) << 4);
        __builtin_amdgcn_global_load_lds((AS1 unsigned int*)((const char*)Ag + srcb),
                                         (AS3 unsigned int*)(dst + (i << 4)), 16, 0, 0);
    }
}
__device__ __forceinline__ void stageB64(const unsigned short* Bg, int kb, int K, char* dst, int tid) {
    // 128x64 bf16 = 1024 16B-chunks; thread handles chunks tid + {0,512}
#pragma unroll
    for (int r = 0; r < 2; ++r) {
        int i = (r << 9) + tid;
        int row = i >> 3, s = i & 7;
        size_t srcb = (size_t)row * ((size_t)K << 1) + ((size_t)kb << 1) + ((s ^ (row & 7)) << 4);
        __builtin_amdgcn_global_load_lds((AS1 unsigned int*)((const char*)Bg + srcb),
                                         (AS3 unsigned int*)(dst + (i << 4)), 16, 0, 0);
    }
}
__device__ __forceinline__ bf16x8 rd64(const char* base, int row, int ks, int lane) {
    int off = (row << 7) + ((((ks << 2) + (lane >> 4)) ^ (row & 7)) << 4);
    return *(const bf16x8*)(base + off);
}

template <int OUTMODE>  // 0: bf16 out, 1: fp32 out + bias
__global__ __launch_bounds__(512, 2)
void gemm256x128_kernel(const unsigned short* __restrict__ A, const unsigned short* __restrict__ Bt,
                        unsigned short* __restrict__ obf, float* __restrict__ of32,
                        const float* __restrict__ bias, int M, int N, int K, int ntx) {
    __shared__ char smem[131072];     // A: [0,96KB) 3 slots; B: [96KB,128KB) 2 slots
    int tid = threadIdx.x, lane = tid & 63, w = tid >> 6;
    int wm = w >> 1, wn = w & 1;      // 4Mx2N wave grid, 64x64 C per wave

    // bijective XCD-aware remap
    int nwg = gridDim.x;
    int qq = nwg >> 3, rr = nwg & 7;
    int orig = blockIdx.x;
    int xcd = orig & 7, lin = orig >> 3;
    int wg = (xcd < rr ? xcd * (qq + 1) : rr * (qq + 1) + (xcd - rr) * qq) + lin;
    int by = wg / ntx, bx = wg - by * ntx;
    int m0 = by << 8, n0 = bx << 7;
    const unsigned short* Ag = A + (size_t)m0 * K;
    const unsigned short* Bg = Bt + (size_t)n0 * K;
    int nkt = K >> 6;

    f32x4 zz = {0.f, 0.f, 0.f, 0.f};
    f32x4 acc[4][4];
#pragma unroll
    for (int a = 0; a < 4; ++a)
#pragma unroll
        for (int b = 0; b < 4; ++b) acc[a][b] = zz;

    // prologue: B(0), A(0), A(1); wait all but A(1)'s 4
    stageB64(Bg, 0, K, smem + 98304, tid);
    stageA64(Ag, 0, K, smem, tid);
    if (nkt > 1) stageA64(Ag, 64, K, smem + 32768, tid);
    if (nkt > 1) asm volatile("s_waitcnt vmcnt(4)" ::: "memory");
    else         asm volatile("s_waitcnt vmcnt(0)" ::: "memory");
    asm volatile("s_barrier" ::: "memory");

    for (int t = 0; t < nkt; ++t) {
        const char* Ab = smem + (t % 3) * 32768;
        const char* Bb = smem + 98304 + (t & 1) * 16384;

        // ---- phase 0: read A-frags (both ksteps) + B-frags 0,1; issue next stages ----
        bf16x8 a0[4], a1[4], b0[2], b1[2];
#pragma unroll
        for (int fm = 0; fm < 4; ++fm) {
            int row = (wm << 6) + (fm << 4) + (lane & 15);
            a0[fm] = rd64(Ab, row, 0, lane);
            a1[fm] = rd64(Ab, row, 1, lane);
        }
#pragma unroll
        for (int j = 0; j < 2; ++j) {
            int row = (wn << 6) + (j << 4) + (lane & 15);
            b0[j] = rd64(Bb, row, 0, lane);
            b1[j] = rd64(Bb, row, 1, lane);
        }
        if (t + 1 < nkt) stageB64(Bg, (t + 1) << 6, K, smem + 98304 + ((t + 1) & 1) * 16384, tid);
        if (t + 2 < nkt) stageA64(Ag, (t + 2) << 6, K, smem + ((t + 2) % 3) * 32768, tid);
        asm volatile("s_barrier" ::: "memory");
        __builtin_amdgcn_s_setprio(1);
#pragma unroll
        for (int fm = 0; fm < 4; ++fm)
#pragma unroll
            for (int j = 0; j < 2; ++j)
                acc[fm][j] = __builtin_amdgcn_mfma_f32_16x16x32_bf16(a0[fm], b0[j], acc[fm][j], 0, 0, 0);
#pragma unroll
        for (int fm = 0; fm < 4; ++fm)
#pragma unroll
            for (int j = 0; j < 2; ++j)
                acc[fm][j] = __builtin_amdgcn_mfma_f32_16x16x32_bf16(a1[fm], b1[j], acc[fm][j], 0, 0, 0);
        __builtin_amdgcn_s_setprio(0);
        asm volatile("s_barrier" ::: "memory");

        // ---- phase 1: B-frags 2,3 (A-frags still live in regs) ----
#pragma unroll
        for (int j = 0; j < 2; ++j) {
            int row = (wn << 6) + ((j + 2) << 4) + (lane & 15);
            b0[j] = rd64(Bb, row, 0, lane);
            b1[j] = rd64(Bb, row, 1, lane);
        }
        asm volatile("s_barrier" ::: "memory");
        __builtin_amdgcn_s_setprio(1);
#pragma unroll
        for (int fm = 0; fm < 4; ++fm)
#pragma unroll
            for (int j = 0; j < 2; ++j)
                acc[fm][j + 2] = __builtin_amdgcn_mfma_f32_16x16x32_bf16(a0[fm], b0[j], acc[fm][j + 2], 0, 0, 0);
#pragma unroll
        for (int fm = 0; fm < 4; ++fm)
#pragma unroll
            for (int j = 0; j < 2; ++j)
                acc[fm][j + 2] = __builtin_amdgcn_mfma_f32_16x16x32_bf16(a1[fm], b1[j], acc[fm][j + 2], 0, 0, 0);
        __builtin_amdgcn_s_setprio(0);
        // counted wait: require A(t+1)+B(t+1) landed; allow A(t+2)'s 4 loads in flight
        if (t + 2 < nkt) asm volatile("s_waitcnt vmcnt(4)" ::: "memory");
        else             asm volatile("s_waitcnt vmcnt(0)" ::: "memory");
        asm volatile("s_barrier" ::: "memory");
    }

    int rbase = m0 + (wm << 6) + ((lane >> 4) << 2);
    int cbase = n0 + (wn << 6) + (lane & 15);
    if (OUTMODE == 0) {
#pragma unroll
        for (int fm = 0; fm < 4; ++fm)
#pragma unroll
            for (int j = 0; j < 4; ++j) {
                size_t ro = (size_t)(rbase + (fm << 4) + j) * N;
#pragma unroll
                for (int fn = 0; fn < 4; ++fn)
                    obf[ro + cbase + (fn << 4)] = f2bf(acc[fm][fn][j]);
            }
    } else {
        float bv[4];
#pragma unroll
        for (int fn = 0; fn < 4; ++fn) bv[fn] = bias[cbase + (fn << 4)];
#pragma unroll
        for (int fm = 0; fm < 4; ++fm)
#pragma unroll
            for (int j = 0; j < 4; ++j) {
                size_t ro = (size_t)(rbase + (fm << 4) + j) * N;
#pragma unroll
                for (int fn = 0; fn < 4; ++fn)
                    of32[ro + cbase + (fn << 4)] = acc[fm][fn][j] + bv[fn];
            }
    }
}

// ---------------- covariance via MFMA: S[bh][c][e] = sum_n k[n,c]*q[n,e], + channel norms ----
__global__ __launch_bounds__(256)
void cov_mfma_kernel(const unsigned short* __restrict__ qkv, float* __restrict__ S,
                     float* __restrict__ qn2, float* __restrict__ kn2) {
    __shared__ unsigned short Kl[96 * 40];   // [channel][token], stride 40 ushorts (80B)
    __shared__ unsigned short Ql[96 * 40];
    int bh = blockIdx.x;
    int b = bh >> 3, h = bh & 7;
    int tok0 = blockIdx.y * 448;
    int tid = threadIdx.x;
    int lane = tid & 63, w = tid >> 6;
    int wr = w & 1, wc = w >> 1;
    int rot = tid & 7;

    f32x4 zz = {0.f, 0.f, 0.f, 0.f};
    f32x4 acc[3][3];
#pragma unroll
    for (int a = 0; a < 3; ++a)
#pragma unroll
        for (int c = 0; c < 3; ++c) acc[a][c] = zz;
    float qn = 0.f, kn = 0.f;

    const uint4* qg = (const uint4*)qkv;   // qkv row = 288 uint4

    for (int step = 0; step < 14; ++step) {
        int tokBase = b * 3136 + tok0 + (step << 5);
        __syncthreads();
#pragma unroll
        for (int r = 0; r < 3; ++r) {
            int idx = (r << 8) + tid;          // 0..767 ; 0..383 = Q, 384..767 = K
            int isK = idx >= 384;
            int j = isK ? idx - 384 : idx;
            int tok = j / 12, c = j % 12;
            uint4 u = qg[(size_t)(tokBase + tok) * 288 + h * 12 + (isK ? 96 : 0) + c];
            unsigned short* dst = isK ? Kl : Ql;
            const unsigned short* us = (const unsigned short*)&u;
#pragma unroll
            for (int i = 0; i < 8; ++i) {
                int e = (i + rot) & 7;
                dst[(c * 8 + e) * 40 + tok] = us[e];
            }
        }
        __syncthreads();
        if (tid < 96) {
#pragma unroll
            for (int t = 0; t < 4; ++t) {
                bf16x8 v = *(const bf16x8*)((const char*)Ql + tid * 80 + (t << 4));
#pragma unroll
                for (int i = 0; i < 8; ++i) { float f = (float)v[i]; qn = fmaf(f, f, qn); }
            }
        } else if (tid >= 128 && tid < 224) {
            int c = tid - 128;
#pragma unroll
            for (int t = 0; t < 4; ++t) {
                bf16x8 v = *(const bf16x8*)((const char*)Kl + c * 80 + (t << 4));
#pragma unroll
                for (int i = 0; i < 8; ++i) { float f = (float)v[i]; kn = fmaf(f, f, kn); }
            }
        }
        int kbyte = (lane >> 4) << 4;
        bf16x8 af[3], bfv[3];
#pragma unroll
        for (int f = 0; f < 3; ++f)
            af[f] = *(const bf16x8*)((const char*)Kl + (wr * 48 + f * 16 + (lane & 15)) * 80 + kbyte);
#pragma unroll
        for (int f = 0; f < 3; ++f)
            bfv[f] = *(const bf16x8*)((const char*)Ql + (wc * 48 + f * 16 + (lane & 15)) * 80 + kbyte);
#pragma unroll
        for (int fm = 0; fm < 3; ++fm)
#pragma unroll
            for (int fn = 0; fn < 3; ++fn)
                acc[fm][fn] = __builtin_amdgcn_mfma_f32_16x16x32_bf16(af[fm], bfv[fn], acc[fm][fn], 0, 0, 0);
    }

    float* Sb = S + (size_t)bh * 9216;
    int rloc = wr * 48 + ((lane >> 4) << 2);
    int cloc = wc * 48 + (lane & 15);
#pragma unroll
    for (int fm = 0; fm < 3; ++fm)
#pragma unroll
        for (int fn = 0; fn < 3; ++fn)
#pragma unroll
            for (int j = 0; j < 4; ++j)
                atomicAdd(&Sb[(rloc + fm * 16 + j) * 96 + cloc + fn * 16], acc[fm][fn][j]);
    if (tid < 96) atomicAdd(&qn2[bh * 96 + tid], qn);
    if (tid >= 128 && tid < 224) atomicAdd(&kn2[bh * 96 + tid - 128], kn);
}

// ---------------- softmax over e of S[c,e]/(||k_c||*||q_e||)*temp[h] -> bf16 attn ----------------
__global__ __launch_bounds__(128)
void softmax_kernel(const float* __restrict__ S, const float* __restrict__ qn2,
                    const float* __restrict__ kn2, const float* __restrict__ temp,
                    unsigned short* __restrict__ attnb) {
    int bh = blockIdx.x, h = bh & 7;
    __shared__ float Sl[96 * 97];
    __shared__ float qinv[96];
    int tid = threadIdx.x;
    const float* Sg = S + (size_t)bh * 9216;
    for (int i = tid; i < 9216; i += 128) Sl[(i / 96) * 97 + (i % 96)] = Sg[i];
    if (tid < 96) qinv[tid] = 1.f / fmaxf(sqrtf(qn2[bh * 96 + tid]), 1e-12f);
    __syncthreads();
    if (tid < 96) {
        int c = tid;
        float scale = (1.f / fmaxf(sqrtf(kn2[bh * 96 + c]), 1e-12f)) * temp[h];
        float* row = &Sl[c * 97];
        float mx = -3.4e38f;
        for (int e = 0; e < 96; ++e) {
            float v = row[e] * scale * qinv[e];
            row[e] = v;
            mx = fmaxf(mx, v);
        }
        float s = 0.f;
        for (int e = 0; e < 96; ++e) {
            float p = __expf(row[e] - mx);
            row[e] = p;
            s += p;
        }
        float inv = 1.f / s;
        unsigned short* ab = attnb + (size_t)bh * 9216 + c * 96;
        for (int e = 0; e < 96; ++e) ab[e] = f2bf(row[e] * inv);
    }
}

// ---------------- Y[n, h*96+c] = sum_e attn[bh][c][e] * v[n][e]  (MFMA, token-major) ----------------
__global__ __launch_bounds__(256)
void attn_v_kernel(const unsigned short* __restrict__ qkv, const unsigned short* __restrict__ attnb,
                   unsigned short* __restrict__ Y) {
    int n0 = blockIdx.x << 6;
    int bh = blockIdx.y;
    int b = bh >> 3, h = bh & 7;
    __shared__ unsigned short Asm[96 * 104];
    __shared__ unsigned short Vs[64 * 104];
    int tid = threadIdx.x;
    int lane = tid & 63, w = tid >> 6;

    const unsigned int* ag = (const unsigned int*)(attnb + (size_t)bh * 9216);
#pragma unroll
    for (int r = 0; r < 18; ++r) {
        int i2 = (r << 8) + tid;
        int c = i2 / 48, ep = i2 % 48;
        *(unsigned int*)&Asm[c * 104 + (ep << 1)] = ag[i2];
    }
    size_t vbase = (size_t)(b * 3136 + n0) * 1152 + 768 + h * 48;
    const unsigned int* vg = (const unsigned int*)qkv;
#pragma unroll
    for (int r = 0; r < 12; ++r) {
        int i2 = (r << 8) + tid;
        int row = i2 / 48, ep = i2 % 48;
        *(unsigned int*)&Vs[row * 104 + (ep << 1)] = vg[vbase + (size_t)row * 1152 + ep];
    }
    __syncthreads();

    f32x4 zz = {0.f, 0.f, 0.f, 0.f};
    f32x4 acc[6];
#pragma unroll
    for (int f = 0; f < 6; ++f) acc[f] = zz;

#pragma unroll
    for (int ks = 0; ks < 3; ++ks) {
        int kbyte = (ks << 6) + ((lane >> 4) << 4);
        bf16x8 av = *(const bf16x8*)((const char*)Vs + ((w << 4) + (lane & 15)) * 208 + kbyte);
#pragma unroll
        for (int fn = 0; fn < 6; ++fn) {
            bf16x8 bv = *(const bf16x8*)((const char*)Asm + ((fn << 4) + (lane & 15)) * 208 + kbyte);
            acc[fn] = __builtin_amdgcn_mfma_f32_16x16x32_bf16(av, bv, acc[fn], 0, 0, 0);
        }
    }

    int rlocal = n0 + (w << 4) + ((lane >> 4) << 2);
#pragma unroll
    for (int fn = 0; fn < 6; ++fn)
#pragma unroll
        for (int j = 0; j < 4; ++j)
            Y[(size_t)(b * 3136 + rlocal + j) * 768 + h * 96 + (fn << 4) + (lane & 15)] = f2bf(acc[fn][j]);
}

// ---------------- launch ----------------
extern "C" void kernel_launch(void* const* d_in, const int* in_sizes, int n_in,
                              void* d_out, int out_size, void* d_ws, size_t ws_size,
                              hipStream_t stream) {
    const float* x     = (const float*)d_in[0];
    const float* Wqkv  = (const float*)d_in[1];
    const float* temp  = (const float*)d_in[2];
    const float* Wproj = (const float*)d_in[3];
    const float* bproj = (const float*)d_in[4];
    float* out = (float*)d_out;
    char* ws = (char*)d_ws;

    unsigned short* xbf    = (unsigned short*)(ws);                 //  77,070,336
    unsigned short* qkvbf  = (unsigned short*)(ws + 77070336);      // 231,211,008
    unsigned short* wqkvt  = (unsigned short*)(ws + 308281344);     //   3,538,944
    unsigned short* wprojt = (unsigned short*)(ws + 311820288);     //   1,179,648
    float*          Sbuf   = (float*)        (ws + 312999936);      //   4,718,592
    float*          qn2    = (float*)        (ws + 317718528);      //      49,152
    float*          kn2    = (float*)        (ws + 317767680);      //      49,152
    unsigned short* attnb  = (unsigned short*)(ws + 317816832);     //   2,359,296
    unsigned short* ybf    = xbf;  // alias: x_bf16 dead after GEMM1

    hipMemsetAsync(Sbuf, 0, 4718592 + 49152 + 49152, stream);

    cvt_f32_bf16_kernel<<<2048, 256, 0, stream>>>((const float4*)x, (ushort4*)xbf, 38535168 / 4);
    transpose_f32_bf16_kernel<<<dim3(72, 24), dim3(32, 8), 0, stream>>>(Wqkv, wqkvt, 768, 2304);
    transpose_f32_bf16_kernel<<<dim3(24, 24), dim3(32, 8), 0, stream>>>(Wproj, wprojt, 768, 768);

    // qkv = x @ Wqkv   [50176 x 2304], bf16 out; grid 196x18 tiles of 256x128
    gemm256x128_kernel<0><<<196 * 18, 512, 0, stream>>>(xbf, wqkvt, qkvbf, nullptr, nullptr,
                                                        50176, 2304, 768, 18);
    // S = K^T Q (per bh), + channel norms
    cov_mfma_kernel<<<dim3(128, 7), 256, 0, stream>>>(qkvbf, Sbuf, qn2, kn2);
    // attn = softmax(S / (|k||q|) * temp)
    softmax_kernel<<<128, 128, 0, stream>>>(Sbuf, qn2, kn2, temp, attnb);
    // Y = V * attn^T  (token-major)
    attn_v_kernel<<<dim3(49, 128), 256, 0, stream>>>(qkvbf, attnb, ybf);
    // out = Y @ Wproj + b   fp32; grid 196x6 tiles of 256x128
    gemm256x128_kernel<1><<<196 * 6, 512, 0, stream>>>(ybf, wprojt, nullptr, out, bproj,
                                                       50176, 768, 768, 6);
}

// Round 6
// 412.794 us; speedup vs baseline: 1.1924x; 1.1557x over previous
//
#include <hip/hip_runtime.h>

using bf16x8 = __attribute__((ext_vector_type(8))) __bf16;
using f32x4  = __attribute__((ext_vector_type(4))) float;

#define AS1 __attribute__((address_space(1)))
#define AS3 __attribute__((address_space(3)))

__device__ __forceinline__ unsigned short f2bf(float f) {
    unsigned int x = __float_as_uint(f);
    x += 0x7fffu + ((x >> 16) & 1u);   // RNE
    return (unsigned short)(x >> 16);
}

// bijective XCD-aware block remap (m204)
__device__ __forceinline__ int xcd_remap(int orig, int nwg) {
    int q = nwg >> 3, r = nwg & 7;
    int xcd = orig & 7, lin = orig >> 3;
    return (xcd < r ? xcd * (q + 1) : r * (q + 1) + (xcd - r) * q) + lin;
}

// ---------------- convert x fp32 -> bf16 ----------------
__global__ void cvt_f32_bf16_kernel(const float4* __restrict__ in, ushort4* __restrict__ out, int n4) {
    int stride = gridDim.x * blockDim.x;
    for (int i = blockIdx.x * blockDim.x + threadIdx.x; i < n4; i += stride) {
        float4 v = in[i];
        ushort4 o;
        o.x = f2bf(v.x); o.y = f2bf(v.y); o.z = f2bf(v.z); o.w = f2bf(v.w);
        out[i] = o;
    }
}

// ---------------- transpose W (K x N) fp32 -> Wt (N x K) bf16 ----------------
__global__ void transpose_f32_bf16_kernel(const float* __restrict__ W, unsigned short* __restrict__ Wt,
                                          int K, int N) {
    __shared__ float tile[32][33];
    int n0 = blockIdx.x << 5, k0 = blockIdx.y << 5;
    int tx = threadIdx.x, ty = threadIdx.y;
#pragma unroll
    for (int i = 0; i < 32; i += 8)
        tile[ty + i][tx] = W[(size_t)(k0 + ty + i) * N + (n0 + tx)];
    __syncthreads();
#pragma unroll
    for (int i = 0; i < 32; i += 8)
        Wt[(size_t)(n0 + ty + i) * K + (k0 + tx)] = f2bf(tile[tx][ty + i]);
}

// ================ proven m97-structure GEMM (R2: 194us, 0 conflicts) + XCD remap ================
// C[M,N] bf16 = A[M,K] * Bt[N,K]^T. 128x128 tile, BK=64, 4 waves, global_load_lds w16,
// (row&7)<<4 XOR swizzle both sides.
__device__ __forceinline__ void stage_tile_128x64(const unsigned short* g, int ldK,
                                                  unsigned short* lds, int tid) {
#pragma unroll
    for (int r = 0; r < 4; ++r) {
        int i = (r << 8) + tid;              // 0..1023 : 16B chunks
        int row = i >> 3;
        int colb = (i & 7) << 4;
        int srcb = row * (ldK << 1) + (colb ^ ((row & 7) << 4));
        __builtin_amdgcn_global_load_lds(
            (AS1 unsigned int*)(unsigned long long)((const char*)g + srcb),
            (AS3 unsigned int*)((char*)lds + (i << 4)),
            16, 0, 0);
    }
}

__device__ __forceinline__ bf16x8 lds_read_swz(const unsigned short* base, int row, int kbyte) {
    int off = (row << 7) + (kbyte ^ ((row & 7) << 4));
    return *(const bf16x8*)((const char*)base + off);
}

__global__ __launch_bounds__(256, 2)
void gemm_bt_kernel(const unsigned short* __restrict__ A, const unsigned short* __restrict__ Bt,
                    unsigned short* __restrict__ obf, int M, int N, int K, int ntx) {
    __shared__ unsigned short As[128 * 64];
    __shared__ unsigned short Bs[128 * 64];
    int tid = threadIdx.x;
    int lane = tid & 63, w = tid >> 6;
    int wm = w >> 1, wn = w & 1;
    int wg = xcd_remap(blockIdx.x, gridDim.x);
    int bx = wg % ntx, by = wg / ntx;
    int m0 = by << 7, n0 = bx << 7;
    const unsigned short* Ag = A + (size_t)m0 * K;
    const unsigned short* Bg = Bt + (size_t)n0 * K;

    f32x4 zz = {0.f, 0.f, 0.f, 0.f};
    f32x4 acc[4][4];
#pragma unroll
    for (int a = 0; a < 4; ++a)
#pragma unroll
        for (int b = 0; b < 4; ++b) acc[a][b] = zz;

    for (int kb = 0; kb < K; kb += 64) {
        stage_tile_128x64(Ag + kb, K, As, tid);
        stage_tile_128x64(Bg + kb, K, Bs, tid);
        __syncthreads();
#pragma unroll
        for (int ks = 0; ks < 2; ++ks) {
            int kbyte = (ks << 6) + ((lane >> 4) << 4);
            bf16x8 af[4], bfr[4];
#pragma unroll
            for (int f = 0; f < 4; ++f)
                af[f] = lds_read_swz(As, (wm << 6) + (f << 4) + (lane & 15), kbyte);
#pragma unroll
            for (int f = 0; f < 4; ++f)
                bfr[f] = lds_read_swz(Bs, (wn << 6) + (f << 4) + (lane & 15), kbyte);
#pragma unroll
            for (int fm = 0; fm < 4; ++fm)
#pragma unroll
                for (int fn = 0; fn < 4; ++fn)
                    acc[fm][fn] = __builtin_amdgcn_mfma_f32_16x16x32_bf16(af[fm], bfr[fn], acc[fm][fn], 0, 0, 0);
        }
        __syncthreads();
    }

    int rbase = m0 + (wm << 6) + ((lane >> 4) << 2);
    int cbase = n0 + (wn << 6) + (lane & 15);
#pragma unroll
    for (int fm = 0; fm < 4; ++fm)
#pragma unroll
        for (int j = 0; j < 4; ++j) {
            size_t ro = (size_t)(rbase + (fm << 4) + j) * N;
#pragma unroll
            for (int fn = 0; fn < 4; ++fn)
                obf[ro + cbase + (fn << 4)] = f2bf(acc[fm][fn][j]);
        }
}

// ================ fused V@M projection GEMM: out[b] = qkvV_b[3136,768] @ MT_b^T + bias ==========
// A = V columns of qkv (lda=2304, ushort offset 1536), per-b. Bt = MT[b] (768x768). fp32 out.
// M=3136 -> 25 tiles of 128 with row clamp + write guard.
__global__ __launch_bounds__(256, 2)
void gemm_v_proj_kernel(const unsigned short* __restrict__ qkv, const unsigned short* __restrict__ MT,
                        float* __restrict__ out, const float* __restrict__ bias) {
    __shared__ unsigned short As[128 * 64];
    __shared__ unsigned short Bs[128 * 64];
    int tid = threadIdx.x;
    int lane = tid & 63, w = tid >> 6;
    int wm = w >> 1, wn = w & 1;
    int wg = xcd_remap(blockIdx.x, gridDim.x);   // nwg = 16*25*6 = 2400
    int bx = wg % 6;
    int t2 = wg / 6;
    int mt = t2 % 25, b = t2 / 25;
    int m0 = mt << 7, n0 = bx << 7;
    const unsigned short* Ab = qkv + (size_t)b * 3136 * 2304 + 1536;   // V block (ushort units)
    const unsigned short* Bg = MT + (size_t)b * 589824 + (size_t)n0 * 768;

    f32x4 zz = {0.f, 0.f, 0.f, 0.f};
    f32x4 acc[4][4];
#pragma unroll
    for (int a = 0; a < 4; ++a)
#pragma unroll
        for (int c = 0; c < 4; ++c) acc[a][c] = zz;

    for (int kb = 0; kb < 768; kb += 64) {
        // A staging: lda=2304, clamp rows past 3135 (tile 24 covers 3072..3199)
#pragma unroll
        for (int r = 0; r < 4; ++r) {
            int i = (r << 8) + tid;
            int row = i >> 3, slot = i & 7;
            int rg = m0 + row; if (rg > 3135) rg = 3135;
            const char* src = (const char*)(Ab + (size_t)rg * 2304 + kb) + ((slot ^ (row & 7)) << 4);
            __builtin_amdgcn_global_load_lds(
                (AS1 unsigned int*)(unsigned long long)src,
                (AS3 unsigned int*)((char*)As + (i << 4)), 16, 0, 0);
        }
        stage_tile_128x64(Bg + kb, 768, Bs, tid);
        __syncthreads();
#pragma unroll
        for (int ks = 0; ks < 2; ++ks) {
            int kbyte = (ks << 6) + ((lane >> 4) << 4);
            bf16x8 af[4], bfr[4];
#pragma unroll
            for (int f = 0; f < 4; ++f)
                af[f] = lds_read_swz(As, (wm << 6) + (f << 4) + (lane & 15), kbyte);
#pragma unroll
            for (int f = 0; f < 4; ++f)
                bfr[f] = lds_read_swz(Bs, (wn << 6) + (f << 4) + (lane & 15), kbyte);
#pragma unroll
            for (int fm = 0; fm < 4; ++fm)
#pragma unroll
                for (int fn = 0; fn < 4; ++fn)
                    acc[fm][fn] = __builtin_amdgcn_mfma_f32_16x16x32_bf16(af[fm], bfr[fn], acc[fm][fn], 0, 0, 0);
        }
        __syncthreads();
    }

    int rloc = m0 + (wm << 6) + ((lane >> 4) << 2);
    int cbase = n0 + (wn << 6) + (lane & 15);
    float bv[4];
#pragma unroll
    for (int fn = 0; fn < 4; ++fn) bv[fn] = bias[cbase + (fn << 4)];
#pragma unroll
    for (int fm = 0; fm < 4; ++fm)
#pragma unroll
        for (int j = 0; j < 4; ++j) {
            int rr = rloc + (fm << 4) + j;
            if (rr < 3136) {
                size_t ro = ((size_t)b * 3136 + rr) * 768;
#pragma unroll
                for (int fn = 0; fn < 4; ++fn)
                    out[ro + cbase + (fn << 4)] = acc[fm][fn][j] + bv[fn];
            }
        }
}

// ---------------- covariance via MFMA: S[bh][c][e] = sum_n k[n,c]*q[n,e], + channel norms ----
__global__ __launch_bounds__(256)
void cov_mfma_kernel(const unsigned short* __restrict__ qkv, float* __restrict__ S,
                     float* __restrict__ qn2, float* __restrict__ kn2) {
    __shared__ unsigned short Kl[96 * 40];   // [channel][token], stride 40 ushorts (80B)
    __shared__ unsigned short Ql[96 * 40];
    int bh = blockIdx.x;
    int b = bh >> 3, h = bh & 7;
    int tok0 = blockIdx.y * 448;
    int tid = threadIdx.x;
    int lane = tid & 63, w = tid >> 6;
    int wr = w & 1, wc = w >> 1;
    int rot = tid & 7;

    f32x4 zz = {0.f, 0.f, 0.f, 0.f};
    f32x4 acc[3][3];
#pragma unroll
    for (int a = 0; a < 3; ++a)
#pragma unroll
        for (int c = 0; c < 3; ++c) acc[a][c] = zz;
    float qn = 0.f, kn = 0.f;

    const uint4* qg = (const uint4*)qkv;   // qkv row = 288 uint4

    for (int step = 0; step < 14; ++step) {
        int tokBase = b * 3136 + tok0 + (step << 5);
        __syncthreads();
#pragma unroll
        for (int r = 0; r < 3; ++r) {
            int idx = (r << 8) + tid;          // 0..767 ; 0..383 = Q, 384..767 = K
            int isK = idx >= 384;
            int j = isK ? idx - 384 : idx;
            int tok = j / 12, c = j % 12;
            uint4 u = qg[(size_t)(tokBase + tok) * 288 + h * 12 + (isK ? 96 : 0) + c];
            unsigned short* dst = isK ? Kl : Ql;
            const unsigned short* us = (const unsigned short*)&u;
#pragma unroll
            for (int i = 0; i < 8; ++i) {
                int e = (i + rot) & 7;
                dst[(c * 8 + e) * 40 + tok] = us[e];
            }
        }
        __syncthreads();
        if (tid < 96) {
#pragma unroll
            for (int t = 0; t < 4; ++t) {
                bf16x8 v = *(const bf16x8*)((const char*)Ql + tid * 80 + (t << 4));
#pragma unroll
                for (int i = 0; i < 8; ++i) { float f = (float)v[i]; qn = fmaf(f, f, qn); }
            }
        } else if (tid >= 128 && tid < 224) {
            int c = tid - 128;
#pragma unroll
            for (int t = 0; t < 4; ++t) {
                bf16x8 v = *(const bf16x8*)((const char*)Kl + c * 80 + (t << 4));
#pragma unroll
                for (int i = 0; i < 8; ++i) { float f = (float)v[i]; kn = fmaf(f, f, kn); }
            }
        }
        int kbyte = (lane >> 4) << 4;
        bf16x8 af[3], bfv[3];
#pragma unroll
        for (int f = 0; f < 3; ++f)
            af[f] = *(const bf16x8*)((const char*)Kl + (wr * 48 + f * 16 + (lane & 15)) * 80 + kbyte);
#pragma unroll
        for (int f = 0; f < 3; ++f)
            bfv[f] = *(const bf16x8*)((const char*)Ql + (wc * 48 + f * 16 + (lane & 15)) * 80 + kbyte);
#pragma unroll
        for (int fm = 0; fm < 3; ++fm)
#pragma unroll
            for (int fn = 0; fn < 3; ++fn)
                acc[fm][fn] = __builtin_amdgcn_mfma_f32_16x16x32_bf16(af[fm], bfv[fn], acc[fm][fn], 0, 0, 0);
    }

    float* Sb = S + (size_t)bh * 9216;
    int rloc = wr * 48 + ((lane >> 4) << 2);
    int cloc = wc * 48 + (lane & 15);
#pragma unroll
    for (int fm = 0; fm < 3; ++fm)
#pragma unroll
        for (int fn = 0; fn < 3; ++fn)
#pragma unroll
            for (int j = 0; j < 4; ++j)
                atomicAdd(&Sb[(rloc + fm * 16 + j) * 96 + cloc + fn * 16], acc[fm][fn][j]);
    if (tid < 96) atomicAdd(&qn2[bh * 96 + tid], qn);
    if (tid >= 128 && tid < 224) atomicAdd(&kn2[bh * 96 + tid - 128], kn);
}

// ---------------- softmax -> attnT[e][c] (transposed, bf16) ----------------
__global__ __launch_bounds__(128)
void softmax_kernel(const float* __restrict__ S, const float* __restrict__ qn2,
                    const float* __restrict__ kn2, const float* __restrict__ temp,
                    unsigned short* __restrict__ attnT) {
    int bh = blockIdx.x, h = bh & 7;
    __shared__ float Sl[96 * 97];
    __shared__ float qinv[96];
    int tid = threadIdx.x;
    const float* Sg = S + (size_t)bh * 9216;
    for (int i = tid; i < 9216; i += 128) Sl[(i / 96) * 97 + (i % 96)] = Sg[i];
    if (tid < 96) qinv[tid] = 1.f / fmaxf(sqrtf(qn2[bh * 96 + tid]), 1e-12f);
    __syncthreads();
    if (tid < 96) {
        int c = tid;
        float scale = (1.f / fmaxf(sqrtf(kn2[bh * 96 + c]), 1e-12f)) * temp[h];
        float* row = &Sl[c * 97];
        float mx = -3.4e38f;
        for (int e = 0; e < 96; ++e) {
            float v = row[e] * scale * qinv[e];
            row[e] = v;
            mx = fmaxf(mx, v);
        }
        float s = 0.f;
        for (int e = 0; e < 96; ++e) {
            float p = __expf(row[e] - mx);
            row[e] = p;
            s += p;
        }
        float inv = 1.f / s;
        unsigned short* ab = attnT + (size_t)bh * 9216;
        for (int e = 0; e < 96; ++e) ab[e * 96 + c] = f2bf(row[e] * inv);
    }
}

// ---------------- M precompute: MT[b][o][h*96+e] = sum_c attnT[bh][e][c] * wprojt[o][h*96+c] ----
// grid 512 = 128 bh x 4 o-chunks(192); 4 waves, wave covers 48 o. No LDS (all L2-hot).
__global__ __launch_bounds__(256)
void attn_M_kernel(const unsigned short* __restrict__ attnT, const unsigned short* __restrict__ wprojt,
                   unsigned short* __restrict__ MT) {
    int bh = blockIdx.x >> 2, oc = blockIdx.x & 3;
    int b = bh >> 3, h = bh & 7;
    int tid = threadIdx.x, lane = tid & 63, w = tid >> 6;
    int o0 = oc * 192 + w * 48;
    const unsigned short* At = attnT + (size_t)bh * 9216;

    f32x4 zz = {0.f, 0.f, 0.f, 0.f};
    f32x4 acc[6][3];
#pragma unroll
    for (int f = 0; f < 6; ++f)
#pragma unroll
        for (int g = 0; g < 3; ++g) acc[f][g] = zz;

#pragma unroll
    for (int ks = 0; ks < 3; ++ks) {
        int koff = ks * 32 + ((lane >> 4) << 3);
        bf16x8 a[6], bb[3];
#pragma unroll
        for (int f = 0; f < 6; ++f)
            a[f] = *(const bf16x8*)(At + (size_t)(f * 16 + (lane & 15)) * 96 + koff);
#pragma unroll
        for (int g = 0; g < 3; ++g)
            bb[g] = *(const bf16x8*)(wprojt + (size_t)(o0 + g * 16 + (lane & 15)) * 768 + h * 96 + koff);
#pragma unroll
        for (int f = 0; f < 6; ++f)
#pragma unroll
            for (int g = 0; g < 3; ++g)
                acc[f][g] = __builtin_amdgcn_mfma_f32_16x16x32_bf16(a[f], bb[g], acc[f][g], 0, 0, 0);
    }

    // D: row=e (f*16 + (lane>>4)*4 + j), col=o (o0 + g*16 + (lane&15)); store MT[b][o][h*96+e]
#pragma unroll
    for (int f = 0; f < 6; ++f)
#pragma unroll
        for (int g = 0; g < 3; ++g) {
            int e = f * 16 + ((lane >> 4) << 2);
            int o = o0 + g * 16 + (lane & 15);
            ushort4 pk;
            pk.x = f2bf(acc[f][g][0]); pk.y = f2bf(acc[f][g][1]);
            pk.z = f2bf(acc[f][g][2]); pk.w = f2bf(acc[f][g][3]);
            *(ushort4*)&MT[((size_t)b * 768 + o) * 768 + h * 96 + e] = pk;
        }
}

// ---------------- launch ----------------
extern "C" void kernel_launch(void* const* d_in, const int* in_sizes, int n_in,
                              void* d_out, int out_size, void* d_ws, size_t ws_size,
                              hipStream_t stream) {
    const float* x     = (const float*)d_in[0];
    const float* Wqkv  = (const float*)d_in[1];
    const float* temp  = (const float*)d_in[2];
    const float* Wproj = (const float*)d_in[3];
    const float* bproj = (const float*)d_in[4];
    float* out = (float*)d_out;
    char* ws = (char*)d_ws;

    unsigned short* xbf    = (unsigned short*)(ws);                 //  77,070,336
    unsigned short* qkvbf  = (unsigned short*)(ws + 77070336);      // 231,211,008
    unsigned short* wqkvt  = (unsigned short*)(ws + 308281344);     //   3,538,944
    unsigned short* wprojt = (unsigned short*)(ws + 311820288);     //   1,179,648
    float*          Sbuf   = (float*)        (ws + 312999936);      //   4,718,592
    float*          qn2    = (float*)        (ws + 317718528);      //      49,152
    float*          kn2    = (float*)        (ws + 317767680);      //      49,152
    unsigned short* attnT  = (unsigned short*)(ws + 317816832);     //   2,359,296
    unsigned short* MT     = xbf;  // alias: x_bf16 dead after GEMM1; MT = 18,874,368 B

    hipMemsetAsync(Sbuf, 0, 4718592 + 49152 + 49152, stream);

    cvt_f32_bf16_kernel<<<2048, 256, 0, stream>>>((const float4*)x, (ushort4*)xbf, 38535168 / 4);
    transpose_f32_bf16_kernel<<<dim3(72, 24), dim3(32, 8), 0, stream>>>(Wqkv, wqkvt, 768, 2304);
    transpose_f32_bf16_kernel<<<dim3(24, 24), dim3(32, 8), 0, stream>>>(Wproj, wprojt, 768, 768);

    // qkv = x @ Wqkv   [50176 x 2304], bf16 out; 392x18 tiles of 128^2, XCD-remapped 1D grid
    gemm_bt_kernel<<<392 * 18, 256, 0, stream>>>(xbf, wqkvt, qkvbf, 50176, 2304, 768, 18);
    // S = K^T Q (per bh), + channel norms
    cov_mfma_kernel<<<dim3(128, 7), 256, 0, stream>>>(qkvbf, Sbuf, qn2, kn2);
    // attnT = softmax(S / (|k||q|) * temp)^T
    softmax_kernel<<<128, 128, 0, stream>>>(Sbuf, qn2, kn2, temp, attnT);
    // MT[b][o][he] = sum_c attn * Wproj
    attn_M_kernel<<<512, 256, 0, stream>>>(attnT, wprojt, MT);
    // out[b] = qkvV_b @ MT_b^T + bias
    gemm_v_proj_kernel<<<2400, 256, 0, stream>>>(qkvbf, MT, out, bproj);
}